// Round 13
// baseline (240.753 us; speedup 1.0000x reference)
//
#include <hip/hip_runtime.h>
#include <hip/hip_fp16.h>
#include <float.h>

#define N_NODES   50000
#define N_EDGES   800000
#define INDIM1    128
#define HC        64
#define N_GRAPHS  64
#define NEG_SLOPE 0.2f
#define CAP       64      // slot capacity/node; deg~Poisson(16); validated R5-R14
#define CSTRIDE   16      // cursor: one counter per 64B line (R12: scatter 54->49us)
#define NWIN      (N_NODES / 8)            // 6250-node dst window per XCD class

// Fused layer-1 grid geometry: 3:2 interleave of transform:scatter blocks (R15).
#define FGROUPS   521
#define FTBLK     (3 * FGROUPS)            // 1563 transform blocks
#define FSBLK     (2 * FGROUPS)            // 1042 scatter blocks
#define FGRID     (5 * FGROUPS + 1)        // 2606 total

// Ledger: R20 fp16 feats (246->236). R21 4B CSR (233.7). R22/R24/R25 LESSONS:
// compiler won't extract loop-carried ILP; occupancy can't replace per-wave
// ILP (needs >=52 VGPR). R26 two-pass softmax: structural straight-line MLP
// -> 225.3 (best). R27: XCD-partitioned scatter. fused1 = write-drain-bound
// (~1TB/s random 64B line flushes; R7 proved packing can't fix). Class
// k = bid&7 (round-robin block->XCD heuristic) handles ONLY dst window
// [k*6250,(k+1)*6250): same-node csr/cursor lines written by ONE XCD, merge
// in its L2 (1.6MB+0.4MB windows << 4MB) -> ~1 line/node instead of 1 line/
// edge. Each class scans all edges; dst reads are L3-resident after pass 1.
typedef _Float16 feat_t;

// ---------------- fused: layer-1 transform + CSR scatter + wedot rider -------
__global__ __launch_bounds__(256, 4) void fused1_kernel(const float* __restrict__ x,
                                                        const float* __restrict__ W,
                                                        const float* __restrict__ att_s,
                                                        const float* __restrict__ att_d,
                                                        feat_t* __restrict__ xs,
                                                        float* __restrict__ a_src,
                                                        float* __restrict__ a_dst,
                                                        const int* __restrict__ src,
                                                        const int* __restrict__ dst,
                                                        const float* __restrict__ eattr,
                                                        int* __restrict__ cursor,
                                                        unsigned int* __restrict__ csr_se,
                                                        const float* __restrict__ We1,
                                                        const float* __restrict__ ae1,
                                                        const float* __restrict__ We2,
                                                        const float* __restrict__ ae2,
                                                        float* __restrict__ wd) {
    constexpr int K4 = INDIM1 / 4;
    constexpr int NPW = 8;
    __shared__ float4 Wsh[K4 * 64];       // [k4][col]: 32KB
    __shared__ float4 xsh[4][2][K4];      // [wave][node-in-pair][k4]
    int bid = blockIdx.x;
    int t = threadIdx.x;

    if (bid == FGRID - 1) {
        // wedot rider block (R13-validated)
        if (t < 128) {
            const float* We = (t < 64) ? We1 : We2;
            const float* ae = (t < 64) ? ae1 : ae2;
            int l = t & 63;
            float p = We[l] * ae[l];
            for (int off = 1; off < 16; off <<= 1) p += __shfl_xor(p, off);
            if ((l & 15) == 0) wd[(t >> 6) * 4 + (l >> 4)] = p;
        }
        return;
    }

    int grp = bid / 5;
    int rem = bid - grp * 5;
    if (rem >= 3) {
        // ---- R27 XCD-partitioned scatter (block-uniform; returns pre-barrier)
        int k = bid & 7;                  // presumed XCD (round-robin heuristic)
        // class-local rank: scatter bids (m%5>=3) below bid with m&7==k.
        // period lcm(5,8)=40 contains 16 scatter bids, exactly 2 per class.
        int r = (bid / 40) * 2;
        int ph = bid - (bid / 40) * 40;
        for (int m = 0; m < ph; ++m)
            if ((m % 5) >= 3 && (m & 7) == k) ++r;
        int Rk = 130 + ((k == 3) || (k == 4));   // class sizes over 2605 bids
        int lo = k * NWIN, hi = lo + NWIN;
        for (int e = r * 256 + t; e < N_EDGES; e += Rk * 256) {
            int d = dst[e];
            if (d >= lo && d < hi) {
                int c = atomicAdd(&cursor[(size_t)d * CSTRIDE], 1);
                if (c < CAP) {
                    unsigned int pk = (unsigned int)(src[e] & 0xFFFF)
                                    | ((unsigned int)__half_as_ushort(__float2half(eattr[e])) << 16);
                    csr_se[(size_t)d * CAP + c] = pk;
                }
            }
        }
        return;
    }

    // ---- transform path, block id 0..1562
    int tb = grp * 3 + rem;
    for (int i = t; i < K4 * 64; i += 256) {
        int k4 = i >> 6, col = i & 63;
        Wsh[i] = make_float4(W[(4 * k4 + 0) * 64 + col], W[(4 * k4 + 1) * 64 + col],
                             W[(4 * k4 + 2) * 64 + col], W[(4 * k4 + 3) * 64 + col]);
    }
    __syncthreads();
    int w = t >> 6, lane = t & 63;
    float avs = att_s[lane], avd = att_d[lane];
    int node0 = tb * (4 * NPW) + w * NPW;
    for (int ng = 0; ng < NPW; ng += 2) {
        int nbase = node0 + ng;
        if (nbase >= N_NODES) return;     // wave-uniform
        for (int q = lane; q < 2 * K4; q += 64) {
            int nn = q / K4, kk = q - nn * K4;
            int node = nbase + nn;
            xsh[w][nn][kk] = (node < N_NODES)
                ? ((const float4*)(x + (size_t)node * INDIM1))[kk]
                : make_float4(0.f, 0.f, 0.f, 0.f);
        }
        float acc0 = 0.f, acc1 = 0.f;
#pragma unroll 4
        for (int k4 = 0; k4 < K4; ++k4) {
            float4 wv = Wsh[k4 * 64 + lane];          // 1 b128 read feeds 8 fmas
            float4 x0 = xsh[w][0][k4];
            float4 x1 = xsh[w][1][k4];
            acc0 = fmaf(x0.x, wv.x, acc0);
            acc0 = fmaf(x0.y, wv.y, acc0);
            acc0 = fmaf(x0.z, wv.z, acc0);
            acc0 = fmaf(x0.w, wv.w, acc0);
            acc1 = fmaf(x1.x, wv.x, acc1);
            acc1 = fmaf(x1.y, wv.y, acc1);
            acc1 = fmaf(x1.z, wv.z, acc1);
            acc1 = fmaf(x1.w, wv.w, acc1);
        }
#pragma unroll
        for (int nn = 0; nn < 2; ++nn) {
            int node = nbase + nn;
            if (node >= N_NODES) break;
            float a = nn ? acc1 : acc0;
            xs[(size_t)node * 64 + lane] = (feat_t)a;
            float ps = a * avs;
            float pd = a * avd;
            for (int off = 1; off < 16; off <<= 1) {
                ps += __shfl_xor(ps, off);
                pd += __shfl_xor(pd, off);
            }
            if ((lane & 15) == 0) {
                a_src[node * 4 + (lane >> 4)] = ps;
                a_dst[node * 4 + (lane >> 4)] = pd;
            }
        }
    }
}

// R26 two-pass softmax building blocks (named registers only; rule: no
// runtime-indexed arrays -> scratch).
#define ALPHA_IT(N, I)                                                          \
    {                                                                           \
        int j = beg##N + I * 16 + e_idx;                                        \
        float a = -FLT_MAX;                                                     \
        if (j < end##N) {                                                       \
            unsigned int se = csr_se[j];                                        \
            sv##N##I = (int)(se & 0xFFFFu);                                     \
            float ea = __half2float(__ushort_as_half((unsigned short)(se >> 16)));\
            float as = a_src[sv##N##I * 4 + h4];                                \
            a = as + adv##N + ea * wdv;                                         \
            a = a > 0.f ? a : NEG_SLOPE * a;                                    \
        }                                                                       \
        w##N##I = a;                                                            \
        float cm = a;                                                           \
        cm = fmaxf(cm, __shfl_xor(cm, 4));                                      \
        cm = fmaxf(cm, __shfl_xor(cm, 8));                                      \
        cm = fmaxf(cm, __shfl_xor(cm, 16));                                     \
        cm = fmaxf(cm, __shfl_xor(cm, 32));                                     \
        m##N = fmaxf(m##N, cm);                                                 \
    }

#define GATHER_IT(N, I)                                                         \
    {                                                                           \
        _Pragma("unroll")                                                       \
        for (int e = 0; e < 16; ++e) {                                          \
            int svb = __builtin_amdgcn_readlane(sv##N##I, e << 2);              \
            float wg = __shfl(w##N##I, (e << 2) | h2);                          \
            acc##N##I = fmaf(wg, (float)xs[(size_t)svb * 64 + lane], acc##N##I);\
        }                                                                       \
    }

// Declares state, runs both passes for nodes A,B. Leaves resA/resB.
#define AGG_CORE                                                                \
    int svA0 = 0, svA1 = 0, svA2 = 0, svA3 = 0;                                 \
    int svB0 = 0, svB1 = 0, svB2 = 0, svB3 = 0;                                 \
    float wA0 = -FLT_MAX, wA1 = -FLT_MAX, wA2 = -FLT_MAX, wA3 = -FLT_MAX;       \
    float wB0 = -FLT_MAX, wB1 = -FLT_MAX, wB2 = -FLT_MAX, wB3 = -FLT_MAX;       \
    float mA = -FLT_MAX, mB = -FLT_MAX;                                         \
    if (nA > 0)  ALPHA_IT(A, 0)                                                 \
    if (nB > 0)  ALPHA_IT(B, 0)                                                 \
    if (nA > 16) ALPHA_IT(A, 1)                                                 \
    if (nB > 16) ALPHA_IT(B, 1)                                                 \
    if (nA > 32) ALPHA_IT(A, 2)                                                 \
    if (nB > 32) ALPHA_IT(B, 2)                                                 \
    if (nA > 48) ALPHA_IT(A, 3)                                                 \
    if (nB > 48) ALPHA_IT(B, 3)                                                 \
    float mmA = (nA > 0) ? mA : 0.f;      /* deg=0: wgt=exp(-inf)=0 */          \
    float mmB = (nB > 0) ? mB : 0.f;                                            \
    wA0 = __expf(wA0 - mmA); wA1 = __expf(wA1 - mmA);                           \
    wA2 = __expf(wA2 - mmA); wA3 = __expf(wA3 - mmA);                           \
    wB0 = __expf(wB0 - mmB); wB1 = __expf(wB1 - mmB);                           \
    wB2 = __expf(wB2 - mmB); wB3 = __expf(wB3 - mmB);                           \
    float sA = (wA0 + wA1) + (wA2 + wA3);                                       \
    float sB = (wB0 + wB1) + (wB2 + wB3);                                       \
    sA += __shfl_xor(sA, 4);  sB += __shfl_xor(sB, 4);                          \
    sA += __shfl_xor(sA, 8);  sB += __shfl_xor(sB, 8);                          \
    sA += __shfl_xor(sA, 16); sB += __shfl_xor(sB, 16);                         \
    sA += __shfl_xor(sA, 32); sB += __shfl_xor(sB, 32);                         \
    float accA0 = 0.f, accA1 = 0.f, accA2 = 0.f, accA3 = 0.f;                   \
    float accB0 = 0.f, accB1 = 0.f, accB2 = 0.f, accB3 = 0.f;                   \
    if (nA > 0)  GATHER_IT(A, 0)                                                \
    if (nB > 0)  GATHER_IT(B, 0)                                                \
    if (nA > 16) GATHER_IT(A, 1)                                                \
    if (nB > 16) GATHER_IT(B, 1)                                                \
    if (nA > 32) GATHER_IT(A, 2)                                                \
    if (nB > 32) GATHER_IT(B, 2)                                                \
    if (nA > 48) GATHER_IT(A, 3)                                                \
    if (nB > 48) GATHER_IT(B, 3)                                                \
    float accA = (accA0 + accA1) + (accA2 + accA3);                             \
    float accB = (accB0 + accB1) + (accB2 + accB3);                             \
    float shA = __shfl(sA, h2);                                                 \
    float shB = __shfl(sB, h2);                                                 \
    float resA = ((shA > 0.f) ? accA / shA : 0.f) + bv;                         \
    float resB = ((shB > 0.f) ? accB / shB : 0.f) + bv;

// ---------------- agg1 + fused layer-2 transform (R26 two-pass) --------------
__global__ __launch_bounds__(256, 4) void agg1_kernel(const feat_t* __restrict__ xs,
                                                      const unsigned int* __restrict__ csr_se,
                                                      const int* __restrict__ degp,
                                                      const float* __restrict__ a_src,
                                                      const float* __restrict__ a_dst,
                                                      const float* __restrict__ wd,
                                                      const float* __restrict__ bias,
                                                      const float* __restrict__ W2,
                                                      const float* __restrict__ as2,
                                                      const float* __restrict__ ad2,
                                                      feat_t* __restrict__ xs2,
                                                      float* __restrict__ asrc2,
                                                      float* __restrict__ adst2) {
    __shared__ float W2sh[64 * 64];       // 16KB
    __shared__ float hshA[4][64];
    __shared__ float hshB[4][64];
    int t = threadIdx.x;
    // stage W2 early; no barrier until after the gather loop
#pragma unroll
    for (int i = 0; i < 4; ++i)
        ((float4*)W2sh)[t + 256 * i] = ((const float4*)W2)[t + 256 * i];

    int w = t >> 6, lane = t & 63;
    const int e_idx = lane >> 2;
    const int h4 = lane & 3;
    const int h2 = lane >> 4;
    int nodeA = blockIdx.x * 8 + w * 2;    // 6250*8 == N_NODES exactly
    int nodeB = nodeA + 1;

    float wdv = wd[h4];
    float bv = bias[lane];
    float avs2 = as2[lane], avd2 = ad2[lane];
    float advA = a_dst[nodeA * 4 + h4];
    float advB = a_dst[nodeB * 4 + h4];
    int nA = min(degp[(size_t)nodeA * CSTRIDE], CAP);
    int nB = min(degp[(size_t)nodeB * CSTRIDE], CAP);
    int begA = nodeA * CAP, endA = begA + nA;
    int begB = nodeB * CAP, endB = begB + nB;

    AGG_CORE

    // h = relu(layer1_out + b1)
    float hA = fmaxf(resA, 0.f);
    float hB = fmaxf(resB, 0.f);

    hshA[w][lane] = hA;
    hshB[w][lane] = hB;
    __syncthreads();                      // W2sh complete; all 256 reach this

    float acc2A = 0.f, acc2B = 0.f;
#pragma unroll
    for (int k4 = 0; k4 < 16; ++k4) {
        float4 ha = ((const float4*)hshA[w])[k4];   // wave-broadcast
        float4 hb = ((const float4*)hshB[w])[k4];
        float w0 = W2sh[(4 * k4 + 0) * 64 + lane];
        float w1 = W2sh[(4 * k4 + 1) * 64 + lane];
        float w2 = W2sh[(4 * k4 + 2) * 64 + lane];
        float w3 = W2sh[(4 * k4 + 3) * 64 + lane];
        acc2A = fmaf(ha.x, w0, acc2A); acc2B = fmaf(hb.x, w0, acc2B);
        acc2A = fmaf(ha.y, w1, acc2A); acc2B = fmaf(hb.y, w1, acc2B);
        acc2A = fmaf(ha.z, w2, acc2A); acc2B = fmaf(hb.z, w2, acc2B);
        acc2A = fmaf(ha.w, w3, acc2A); acc2B = fmaf(hb.w, w3, acc2B);
    }
    xs2[(size_t)nodeA * 64 + lane] = (feat_t)acc2A;
    xs2[(size_t)nodeB * 64 + lane] = (feat_t)acc2B;
    float psA = acc2A * avs2, pdA = acc2A * avd2;
    float psB = acc2B * avs2, pdB = acc2B * avd2;
    for (int off = 1; off < 16; off <<= 1) {
        psA += __shfl_xor(psA, off);
        pdA += __shfl_xor(pdA, off);
        psB += __shfl_xor(psB, off);
        pdB += __shfl_xor(pdB, off);
    }
    if ((lane & 15) == 0) {
        asrc2[nodeA * 4 + (lane >> 4)] = psA;
        adst2[nodeA * 4 + (lane >> 4)] = pdA;
        asrc2[nodeB * 4 + (lane >> 4)] = psB;
        adst2[nodeB * 4 + (lane >> 4)] = pdB;
    }
}

// ---------------- agg2 + fused mean-pool (R26 two-pass) ----------------------
__global__ __launch_bounds__(256, 4) void agg2_kernel(const feat_t* __restrict__ xs,
                                                      const unsigned int* __restrict__ csr_se,
                                                      const int* __restrict__ degp,
                                                      const float* __restrict__ a_src,
                                                      const float* __restrict__ a_dst,
                                                      const float* __restrict__ wd,
                                                      const float* __restrict__ bias,
                                                      const int* __restrict__ batch,
                                                      float* __restrict__ gout) {
    __shared__ float plds[256];
    int t = threadIdx.x;
    int w = t >> 6, lane = t & 63;
    const int e_idx = lane >> 2;
    const int h4 = lane & 3;
    const int h2 = lane >> 4;
    int nodeA = blockIdx.x * 8 + w * 2;
    int nodeB = nodeA + 1;

    float wdv = wd[h4];
    float bv = bias[lane];
    float advA = a_dst[nodeA * 4 + h4];
    float advB = a_dst[nodeB * 4 + h4];
    int nA = min(degp[(size_t)nodeA * CSTRIDE], CAP);
    int nB = min(degp[(size_t)nodeB * CSTRIDE], CAP);
    int begA = nodeA * CAP, endA = begA + nA;
    int begB = nodeB * CAP, endB = begB + nB;

    AGG_CORE

    int gA = batch[nodeA], gB = batch[nodeB];
    int gF = batch[blockIdx.x * 8];
    int gL = batch[blockIdx.x * 8 + 7];
    if (gF == gL) {                             // block-uniform branch
        plds[w * 64 + lane] = resA + resB;
        __syncthreads();
        if (w == 0) {
            float v = plds[lane] + plds[64 + lane] +
                      plds[128 + lane] + plds[192 + lane];
            atomicAdd(&gout[gF * 64 + lane], v);
        }
    } else {
        if (gA == gB) {
            atomicAdd(&gout[gA * 64 + lane], resA + resB);
        } else {
            atomicAdd(&gout[gA * 64 + lane], resA);
            atomicAdd(&gout[gB * 64 + lane], resB);
        }
    }
}

__global__ void pool_div_kernel(float* __restrict__ out, const int* __restrict__ batch) {
    int g = blockIdx.x, t = threadIdx.x;
    int lo = 0, hi = N_NODES;
    while (lo < hi) { int mid = (lo + hi) >> 1; if (batch[mid] < g) lo = mid + 1; else hi = mid; }
    int lo2 = lo, hi2 = N_NODES;
    while (lo2 < hi2) { int mid = (lo2 + hi2) >> 1; if (batch[mid] <= g) lo2 = mid + 1; else hi2 = mid; }
    float c = (float)max(lo2 - lo, 1);
    out[g * 64 + t] /= c;
}

// ---------------- launch ----------------

extern "C" void kernel_launch(void* const* d_in, const int* in_sizes, int n_in,
                              void* d_out, int out_size, void* d_ws, size_t ws_size,
                              hipStream_t stream) {
    const float* x    = (const float*)d_in[0];
    const int*   eidx = (const int*)d_in[1];
    const float* eat  = (const float*)d_in[2];
    const int*   batch= (const int*)d_in[3];
    const float* W1   = (const float*)d_in[4];
    const float* We1  = (const float*)d_in[5];
    const float* as1  = (const float*)d_in[6];
    const float* ad1  = (const float*)d_in[7];
    const float* ae1  = (const float*)d_in[8];
    const float* b1   = (const float*)d_in[9];
    const float* W2   = (const float*)d_in[10];
    const float* We2  = (const float*)d_in[11];
    const float* as2  = (const float*)d_in[12];
    const float* ad2  = (const float*)d_in[13];
    const float* ae2  = (const float*)d_in[14];
    const float* b2   = (const float*)d_in[15];
    const int* src  = eidx;             // edge_index[0]
    const int* dstp = eidx + N_EDGES;   // edge_index[1]
    float* out = (float*)d_out;

    char* p = (char*)d_ws;
    auto alloc = [&](size_t bytes) {
        char* r = p;
        p += (bytes + 255) & ~(size_t)255;
        return r;
    };
    unsigned int* csrse = (unsigned int*)alloc((size_t)N_NODES * CAP * 4);  // 12.8 MB
    feat_t* xs     = (feat_t*)alloc((size_t)N_NODES * 64 * 2);     // 6.4 MB fp16
    feat_t* hbuf   = (feat_t*)alloc((size_t)N_NODES * 64 * 2);     // 6.4 MB fp16
    float*  asrc   = (float*)alloc((size_t)N_NODES * 4 * 4);
    float*  adst   = (float*)alloc((size_t)N_NODES * 4 * 4);
    float*  asrc2  = (float*)alloc((size_t)N_NODES * 4 * 4);
    float*  adst2  = (float*)alloc((size_t)N_NODES * 4 * 4);
    float*  wd     = (float*)alloc(64);                            // wd1[4] || wd2[4]
    int*    cursor = (int*)alloc((size_t)N_NODES * CSTRIDE * 4);   // 3.2 MB padded

    hipMemsetAsync(cursor, 0, (size_t)N_NODES * CSTRIDE * 4, stream);
    hipMemsetAsync(d_out, 0, (size_t)N_GRAPHS * 64 * 4, stream);

    const int NB = N_NODES / 8;                            // 6250 (×8 == N_NODES)

    // layer 1: fused transform + XCD-partitioned scatter + wedot rider (R27)
    fused1_kernel<<<FGRID, 256, 0, stream>>>(x, W1, as1, ad1, xs, asrc, adst,
                                             src, dstp, eat, cursor, csrse,
                                             We1, ae1, We2, ae2, wd);
    // aggregate layer 1 + fused layer-2 transform (R26 two-pass)
    agg1_kernel<<<NB, 256, 0, stream>>>(xs, csrse, cursor, asrc, adst,
                                        wd, b1, W2, as2, ad2,
                                        hbuf, asrc2, adst2);
    // aggregate layer 2 + fused mean-pool (R26 two-pass)
    agg2_kernel<<<NB, 256, 0, stream>>>(hbuf, csrse, cursor, asrc2, adst2,
                                        wd + 4, b2, batch, out);
    pool_div_kernel<<<N_GRAPHS, 64, 0, stream>>>(out, batch);
}

// Round 14
// 224.527 us; speedup vs baseline: 1.0723x; 1.0723x over previous
//
#include <hip/hip_runtime.h>
#include <hip/hip_fp16.h>
#include <float.h>

#define N_NODES   50000
#define N_EDGES   800000
#define INDIM1    128
#define HC        64
#define N_GRAPHS  64
#define NEG_SLOPE 0.2f
#define CAP       64      // slot capacity/node; deg~Poisson(16); validated R5-R14
#define CSTRIDE   16      // cursor: one counter per 64B line (R12: scatter 54->49us)

// Fused layer-1 grid geometry: 3:2 interleave of transform:scatter blocks (R15).
#define FGROUPS   521
#define FTBLK     (3 * FGROUPS)            // 1563 transform blocks
#define FSBLK     (2 * FGROUPS)            // 1042 scatter blocks
#define FGRID     (5 * FGROUPS + 1)        // 2606 total
#define ESTRIDE   (FSBLK * 256)            // 266752 edge stride

// FINAL LEDGER (best = 225.3us, this config):
// R15 scatter||transform fuse (298->269). R16-R19 W2-fusion into agg1 (3
// attempts; works at 256thr/VGPR>=52). R17 pool-in-agg2 + 2-chain ILP
// (277->250). R20 fp16 feats (246->236). R21 4B CSR (233.7). R26 two-pass
// straight-line softmax (233.7->225.3). REJECTED BY MEASUREMENT: >2 chains
// (R22), scatter unroll (R23), csr prefetch+split acc (R24), occupancy raise
// (R25: VGPR 40 -> 89us), XCD-partitioned scatter (R27: -13MB write but
// +32MB fetch). Floors: fused1 = 73.8MB at ~1.2TB/s random-line drain;
// aggs = latency/traffic with per-wave ILP saturated at VGPR 52.
typedef _Float16 feat_t;

// ---------------- fused: layer-1 transform + CSR scatter + wedot rider -------
__global__ __launch_bounds__(256, 4) void fused1_kernel(const float* __restrict__ x,
                                                        const float* __restrict__ W,
                                                        const float* __restrict__ att_s,
                                                        const float* __restrict__ att_d,
                                                        feat_t* __restrict__ xs,
                                                        float* __restrict__ a_src,
                                                        float* __restrict__ a_dst,
                                                        const int* __restrict__ src,
                                                        const int* __restrict__ dst,
                                                        const float* __restrict__ eattr,
                                                        int* __restrict__ cursor,
                                                        unsigned int* __restrict__ csr_se,
                                                        const float* __restrict__ We1,
                                                        const float* __restrict__ ae1,
                                                        const float* __restrict__ We2,
                                                        const float* __restrict__ ae2,
                                                        float* __restrict__ wd) {
    constexpr int K4 = INDIM1 / 4;
    constexpr int NPW = 8;
    __shared__ float4 Wsh[K4 * 64];       // [k4][col]: 32KB
    __shared__ float4 xsh[4][2][K4];      // [wave][node-in-pair][k4]
    int bid = blockIdx.x;
    int t = threadIdx.x;

    if (bid == FGRID - 1) {
        // wedot rider block (R13-validated)
        if (t < 128) {
            const float* We = (t < 64) ? We1 : We2;
            const float* ae = (t < 64) ? ae1 : ae2;
            int l = t & 63;
            float p = We[l] * ae[l];
            for (int off = 1; off < 16; off <<= 1) p += __shfl_xor(p, off);
            if ((l & 15) == 0) wd[(t >> 6) * 4 + (l >> 4)] = p;
        }
        return;
    }

    int grp = bid / 5;
    int rem = bid - grp * 5;
    if (rem >= 3) {
        // ---- scatter path (block-uniform branch; returns before syncthreads)
        int sb = grp * 2 + (rem - 3);     // 0..1041
        for (int e = sb * 256 + t; e < N_EDGES; e += ESTRIDE) {
            int d = dst[e];
            int c = atomicAdd(&cursor[(size_t)d * CSTRIDE], 1);
            if (c < CAP) {
                unsigned int pk = (unsigned int)(src[e] & 0xFFFF)
                                | ((unsigned int)__half_as_ushort(__float2half(eattr[e])) << 16);
                csr_se[(size_t)d * CAP + c] = pk;
            }
        }
        return;
    }

    // ---- transform path, block id 0..1562
    int tb = grp * 3 + rem;
    for (int i = t; i < K4 * 64; i += 256) {
        int k4 = i >> 6, col = i & 63;
        Wsh[i] = make_float4(W[(4 * k4 + 0) * 64 + col], W[(4 * k4 + 1) * 64 + col],
                             W[(4 * k4 + 2) * 64 + col], W[(4 * k4 + 3) * 64 + col]);
    }
    __syncthreads();
    int w = t >> 6, lane = t & 63;
    float avs = att_s[lane], avd = att_d[lane];
    int node0 = tb * (4 * NPW) + w * NPW;
    for (int ng = 0; ng < NPW; ng += 2) {
        int nbase = node0 + ng;
        if (nbase >= N_NODES) return;     // wave-uniform
        for (int q = lane; q < 2 * K4; q += 64) {
            int nn = q / K4, kk = q - nn * K4;
            int node = nbase + nn;
            xsh[w][nn][kk] = (node < N_NODES)
                ? ((const float4*)(x + (size_t)node * INDIM1))[kk]
                : make_float4(0.f, 0.f, 0.f, 0.f);
        }
        float acc0 = 0.f, acc1 = 0.f;
#pragma unroll 4
        for (int k4 = 0; k4 < K4; ++k4) {
            float4 wv = Wsh[k4 * 64 + lane];          // 1 b128 read feeds 8 fmas
            float4 x0 = xsh[w][0][k4];
            float4 x1 = xsh[w][1][k4];
            acc0 = fmaf(x0.x, wv.x, acc0);
            acc0 = fmaf(x0.y, wv.y, acc0);
            acc0 = fmaf(x0.z, wv.z, acc0);
            acc0 = fmaf(x0.w, wv.w, acc0);
            acc1 = fmaf(x1.x, wv.x, acc1);
            acc1 = fmaf(x1.y, wv.y, acc1);
            acc1 = fmaf(x1.z, wv.z, acc1);
            acc1 = fmaf(x1.w, wv.w, acc1);
        }
#pragma unroll
        for (int nn = 0; nn < 2; ++nn) {
            int node = nbase + nn;
            if (node >= N_NODES) break;
            float a = nn ? acc1 : acc0;
            xs[(size_t)node * 64 + lane] = (feat_t)a;
            float ps = a * avs;
            float pd = a * avd;
            for (int off = 1; off < 16; off <<= 1) {
                ps += __shfl_xor(ps, off);
                pd += __shfl_xor(pd, off);
            }
            if ((lane & 15) == 0) {
                a_src[node * 4 + (lane >> 4)] = ps;
                a_dst[node * 4 + (lane >> 4)] = pd;
            }
        }
    }
}

// R26 two-pass softmax building blocks (named registers only; rule: no
// runtime-indexed arrays -> scratch).
#define ALPHA_IT(N, I)                                                          \
    {                                                                           \
        int j = beg##N + I * 16 + e_idx;                                        \
        float a = -FLT_MAX;                                                     \
        if (j < end##N) {                                                       \
            unsigned int se = csr_se[j];                                        \
            sv##N##I = (int)(se & 0xFFFFu);                                     \
            float ea = __half2float(__ushort_as_half((unsigned short)(se >> 16)));\
            float as = a_src[sv##N##I * 4 + h4];                                \
            a = as + adv##N + ea * wdv;                                         \
            a = a > 0.f ? a : NEG_SLOPE * a;                                    \
        }                                                                       \
        w##N##I = a;                                                            \
        float cm = a;                                                           \
        cm = fmaxf(cm, __shfl_xor(cm, 4));                                      \
        cm = fmaxf(cm, __shfl_xor(cm, 8));                                      \
        cm = fmaxf(cm, __shfl_xor(cm, 16));                                     \
        cm = fmaxf(cm, __shfl_xor(cm, 32));                                     \
        m##N = fmaxf(m##N, cm);                                                 \
    }

#define GATHER_IT(N, I)                                                         \
    {                                                                           \
        _Pragma("unroll")                                                       \
        for (int e = 0; e < 16; ++e) {                                          \
            int svb = __builtin_amdgcn_readlane(sv##N##I, e << 2);              \
            float wg = __shfl(w##N##I, (e << 2) | h2);                          \
            acc##N##I = fmaf(wg, (float)xs[(size_t)svb * 64 + lane], acc##N##I);\
        }                                                                       \
    }

// Declares state, runs both passes for nodes A,B. Leaves resA/resB.
#define AGG_CORE                                                                \
    int svA0 = 0, svA1 = 0, svA2 = 0, svA3 = 0;                                 \
    int svB0 = 0, svB1 = 0, svB2 = 0, svB3 = 0;                                 \
    float wA0 = -FLT_MAX, wA1 = -FLT_MAX, wA2 = -FLT_MAX, wA3 = -FLT_MAX;       \
    float wB0 = -FLT_MAX, wB1 = -FLT_MAX, wB2 = -FLT_MAX, wB3 = -FLT_MAX;       \
    float mA = -FLT_MAX, mB = -FLT_MAX;                                         \
    if (nA > 0)  ALPHA_IT(A, 0)                                                 \
    if (nB > 0)  ALPHA_IT(B, 0)                                                 \
    if (nA > 16) ALPHA_IT(A, 1)                                                 \
    if (nB > 16) ALPHA_IT(B, 1)                                                 \
    if (nA > 32) ALPHA_IT(A, 2)                                                 \
    if (nB > 32) ALPHA_IT(B, 2)                                                 \
    if (nA > 48) ALPHA_IT(A, 3)                                                 \
    if (nB > 48) ALPHA_IT(B, 3)                                                 \
    float mmA = (nA > 0) ? mA : 0.f;      /* deg=0: wgt=exp(-inf)=0 */          \
    float mmB = (nB > 0) ? mB : 0.f;                                            \
    wA0 = __expf(wA0 - mmA); wA1 = __expf(wA1 - mmA);                           \
    wA2 = __expf(wA2 - mmA); wA3 = __expf(wA3 - mmA);                           \
    wB0 = __expf(wB0 - mmB); wB1 = __expf(wB1 - mmB);                           \
    wB2 = __expf(wB2 - mmB); wB3 = __expf(wB3 - mmB);                           \
    float sA = (wA0 + wA1) + (wA2 + wA3);                                       \
    float sB = (wB0 + wB1) + (wB2 + wB3);                                       \
    sA += __shfl_xor(sA, 4);  sB += __shfl_xor(sB, 4);                          \
    sA += __shfl_xor(sA, 8);  sB += __shfl_xor(sB, 8);                          \
    sA += __shfl_xor(sA, 16); sB += __shfl_xor(sB, 16);                         \
    sA += __shfl_xor(sA, 32); sB += __shfl_xor(sB, 32);                         \
    float accA0 = 0.f, accA1 = 0.f, accA2 = 0.f, accA3 = 0.f;                   \
    float accB0 = 0.f, accB1 = 0.f, accB2 = 0.f, accB3 = 0.f;                   \
    if (nA > 0)  GATHER_IT(A, 0)                                                \
    if (nB > 0)  GATHER_IT(B, 0)                                                \
    if (nA > 16) GATHER_IT(A, 1)                                                \
    if (nB > 16) GATHER_IT(B, 1)                                                \
    if (nA > 32) GATHER_IT(A, 2)                                                \
    if (nB > 32) GATHER_IT(B, 2)                                                \
    if (nA > 48) GATHER_IT(A, 3)                                                \
    if (nB > 48) GATHER_IT(B, 3)                                                \
    float accA = (accA0 + accA1) + (accA2 + accA3);                             \
    float accB = (accB0 + accB1) + (accB2 + accB3);                             \
    float shA = __shfl(sA, h2);                                                 \
    float shB = __shfl(sB, h2);                                                 \
    float resA = ((shA > 0.f) ? accA / shA : 0.f) + bv;                         \
    float resB = ((shB > 0.f) ? accB / shB : 0.f) + bv;

// ---------------- agg1 + fused layer-2 transform (R26 two-pass) --------------
__global__ __launch_bounds__(256, 4) void agg1_kernel(const feat_t* __restrict__ xs,
                                                      const unsigned int* __restrict__ csr_se,
                                                      const int* __restrict__ degp,
                                                      const float* __restrict__ a_src,
                                                      const float* __restrict__ a_dst,
                                                      const float* __restrict__ wd,
                                                      const float* __restrict__ bias,
                                                      const float* __restrict__ W2,
                                                      const float* __restrict__ as2,
                                                      const float* __restrict__ ad2,
                                                      feat_t* __restrict__ xs2,
                                                      float* __restrict__ asrc2,
                                                      float* __restrict__ adst2) {
    __shared__ float W2sh[64 * 64];       // 16KB
    __shared__ float hshA[4][64];
    __shared__ float hshB[4][64];
    int t = threadIdx.x;
    // stage W2 early; no barrier until after the gather loop
#pragma unroll
    for (int i = 0; i < 4; ++i)
        ((float4*)W2sh)[t + 256 * i] = ((const float4*)W2)[t + 256 * i];

    int w = t >> 6, lane = t & 63;
    const int e_idx = lane >> 2;
    const int h4 = lane & 3;
    const int h2 = lane >> 4;
    int nodeA = blockIdx.x * 8 + w * 2;    // 6250*8 == N_NODES exactly
    int nodeB = nodeA + 1;

    float wdv = wd[h4];
    float bv = bias[lane];
    float avs2 = as2[lane], avd2 = ad2[lane];
    float advA = a_dst[nodeA * 4 + h4];
    float advB = a_dst[nodeB * 4 + h4];
    int nA = min(degp[(size_t)nodeA * CSTRIDE], CAP);
    int nB = min(degp[(size_t)nodeB * CSTRIDE], CAP);
    int begA = nodeA * CAP, endA = begA + nA;
    int begB = nodeB * CAP, endB = begB + nB;

    AGG_CORE

    // h = relu(layer1_out + b1)
    float hA = fmaxf(resA, 0.f);
    float hB = fmaxf(resB, 0.f);

    hshA[w][lane] = hA;
    hshB[w][lane] = hB;
    __syncthreads();                      // W2sh complete; all 256 reach this

    float acc2A = 0.f, acc2B = 0.f;
#pragma unroll
    for (int k4 = 0; k4 < 16; ++k4) {
        float4 ha = ((const float4*)hshA[w])[k4];   // wave-broadcast
        float4 hb = ((const float4*)hshB[w])[k4];
        float w0 = W2sh[(4 * k4 + 0) * 64 + lane];
        float w1 = W2sh[(4 * k4 + 1) * 64 + lane];
        float w2 = W2sh[(4 * k4 + 2) * 64 + lane];
        float w3 = W2sh[(4 * k4 + 3) * 64 + lane];
        acc2A = fmaf(ha.x, w0, acc2A); acc2B = fmaf(hb.x, w0, acc2B);
        acc2A = fmaf(ha.y, w1, acc2A); acc2B = fmaf(hb.y, w1, acc2B);
        acc2A = fmaf(ha.z, w2, acc2A); acc2B = fmaf(hb.z, w2, acc2B);
        acc2A = fmaf(ha.w, w3, acc2A); acc2B = fmaf(hb.w, w3, acc2B);
    }
    xs2[(size_t)nodeA * 64 + lane] = (feat_t)acc2A;
    xs2[(size_t)nodeB * 64 + lane] = (feat_t)acc2B;
    float psA = acc2A * avs2, pdA = acc2A * avd2;
    float psB = acc2B * avs2, pdB = acc2B * avd2;
    for (int off = 1; off < 16; off <<= 1) {
        psA += __shfl_xor(psA, off);
        pdA += __shfl_xor(pdA, off);
        psB += __shfl_xor(psB, off);
        pdB += __shfl_xor(pdB, off);
    }
    if ((lane & 15) == 0) {
        asrc2[nodeA * 4 + (lane >> 4)] = psA;
        adst2[nodeA * 4 + (lane >> 4)] = pdA;
        asrc2[nodeB * 4 + (lane >> 4)] = psB;
        adst2[nodeB * 4 + (lane >> 4)] = pdB;
    }
}

// ---------------- agg2 + fused mean-pool (R26 two-pass) ----------------------
__global__ __launch_bounds__(256, 4) void agg2_kernel(const feat_t* __restrict__ xs,
                                                      const unsigned int* __restrict__ csr_se,
                                                      const int* __restrict__ degp,
                                                      const float* __restrict__ a_src,
                                                      const float* __restrict__ a_dst,
                                                      const float* __restrict__ wd,
                                                      const float* __restrict__ bias,
                                                      const int* __restrict__ batch,
                                                      float* __restrict__ gout) {
    __shared__ float plds[256];
    int t = threadIdx.x;
    int w = t >> 6, lane = t & 63;
    const int e_idx = lane >> 2;
    const int h4 = lane & 3;
    const int h2 = lane >> 4;
    int nodeA = blockIdx.x * 8 + w * 2;
    int nodeB = nodeA + 1;

    float wdv = wd[h4];
    float bv = bias[lane];
    float advA = a_dst[nodeA * 4 + h4];
    float advB = a_dst[nodeB * 4 + h4];
    int nA = min(degp[(size_t)nodeA * CSTRIDE], CAP);
    int nB = min(degp[(size_t)nodeB * CSTRIDE], CAP);
    int begA = nodeA * CAP, endA = begA + nA;
    int begB = nodeB * CAP, endB = begB + nB;

    AGG_CORE

    int gA = batch[nodeA], gB = batch[nodeB];
    int gF = batch[blockIdx.x * 8];
    int gL = batch[blockIdx.x * 8 + 7];
    if (gF == gL) {                             // block-uniform branch
        plds[w * 64 + lane] = resA + resB;
        __syncthreads();
        if (w == 0) {
            float v = plds[lane] + plds[64 + lane] +
                      plds[128 + lane] + plds[192 + lane];
            atomicAdd(&gout[gF * 64 + lane], v);
        }
    } else {
        if (gA == gB) {
            atomicAdd(&gout[gA * 64 + lane], resA + resB);
        } else {
            atomicAdd(&gout[gA * 64 + lane], resA);
            atomicAdd(&gout[gB * 64 + lane], resB);
        }
    }
}

__global__ void pool_div_kernel(float* __restrict__ out, const int* __restrict__ batch) {
    int g = blockIdx.x, t = threadIdx.x;
    int lo = 0, hi = N_NODES;
    while (lo < hi) { int mid = (lo + hi) >> 1; if (batch[mid] < g) lo = mid + 1; else hi = mid; }
    int lo2 = lo, hi2 = N_NODES;
    while (lo2 < hi2) { int mid = (lo2 + hi2) >> 1; if (batch[mid] <= g) lo2 = mid + 1; else hi2 = mid; }
    float c = (float)max(lo2 - lo, 1);
    out[g * 64 + t] /= c;
}

// ---------------- launch ----------------

extern "C" void kernel_launch(void* const* d_in, const int* in_sizes, int n_in,
                              void* d_out, int out_size, void* d_ws, size_t ws_size,
                              hipStream_t stream) {
    const float* x    = (const float*)d_in[0];
    const int*   eidx = (const int*)d_in[1];
    const float* eat  = (const float*)d_in[2];
    const int*   batch= (const int*)d_in[3];
    const float* W1   = (const float*)d_in[4];
    const float* We1  = (const float*)d_in[5];
    const float* as1  = (const float*)d_in[6];
    const float* ad1  = (const float*)d_in[7];
    const float* ae1  = (const float*)d_in[8];
    const float* b1   = (const float*)d_in[9];
    const float* W2   = (const float*)d_in[10];
    const float* We2  = (const float*)d_in[11];
    const float* as2  = (const float*)d_in[12];
    const float* ad2  = (const float*)d_in[13];
    const float* ae2  = (const float*)d_in[14];
    const float* b2   = (const float*)d_in[15];
    const int* src  = eidx;             // edge_index[0]
    const int* dstp = eidx + N_EDGES;   // edge_index[1]
    float* out = (float*)d_out;

    char* p = (char*)d_ws;
    auto alloc = [&](size_t bytes) {
        char* r = p;
        p += (bytes + 255) & ~(size_t)255;
        return r;
    };
    unsigned int* csrse = (unsigned int*)alloc((size_t)N_NODES * CAP * 4);  // 12.8 MB
    feat_t* xs     = (feat_t*)alloc((size_t)N_NODES * 64 * 2);     // 6.4 MB fp16
    feat_t* hbuf   = (feat_t*)alloc((size_t)N_NODES * 64 * 2);     // 6.4 MB fp16
    float*  asrc   = (float*)alloc((size_t)N_NODES * 4 * 4);
    float*  adst   = (float*)alloc((size_t)N_NODES * 4 * 4);
    float*  asrc2  = (float*)alloc((size_t)N_NODES * 4 * 4);
    float*  adst2  = (float*)alloc((size_t)N_NODES * 4 * 4);
    float*  wd     = (float*)alloc(64);                            // wd1[4] || wd2[4]
    int*    cursor = (int*)alloc((size_t)N_NODES * CSTRIDE * 4);   // 3.2 MB padded

    hipMemsetAsync(cursor, 0, (size_t)N_NODES * CSTRIDE * 4, stream);
    hipMemsetAsync(d_out, 0, (size_t)N_GRAPHS * 64 * 4, stream);

    const int NB = N_NODES / 8;                            // 6250 (×8 == N_NODES)

    // layer 1: fused transform + CSR scatter + wedot rider (R15/R7-proven)
    fused1_kernel<<<FGRID, 256, 0, stream>>>(x, W1, as1, ad1, xs, asrc, adst,
                                             src, dstp, eat, cursor, csrse,
                                             We1, ae1, We2, ae2, wd);
    // aggregate layer 1 + fused layer-2 transform (R26 two-pass)
    agg1_kernel<<<NB, 256, 0, stream>>>(xs, csrse, cursor, asrc, adst,
                                        wd, b1, W2, as2, ad2,
                                        hbuf, asrc2, adst2);
    // aggregate layer 2 + fused mean-pool (R26 two-pass)
    agg2_kernel<<<NB, 256, 0, stream>>>(hbuf, csrse, cursor, asrc2, adst2,
                                        wd + 4, b2, batch, out);
    pool_div_kernel<<<N_GRAPHS, 64, 0, stream>>>(out, batch);
}